// Round 12
// baseline (225.136 us; speedup 1.0000x reference)
//
#include <hip/hip_runtime.h>

// BlockSparseAttention B=2,H=16,N=2048,D=64 fp32, block-causal.
// R17: INTRA-WG SPLIT-K. 512-thread WGs, grid 512 (32 bh x 16 qsub128).
// Waves 0-3 = key-group L (tiles [0,w/2)), waves 4-7 = group H ([w/2,w)),
// each group has its own 2x16KB double buffer (64KB LDS, 2 WGs/CU).
// Both groups trip-count w/2 exactly (w always multiple of 4) -> lockstep
// WG barriers, no divergence. Epilogue: H writes 40 f32/thread partials to
// LDS (stride 41, conflict-free), L sums + normalizes + writes O.
// No atomics, no fences, no CU-placement assumptions.
// Model (fits R7/R12/R13/R15 within 3%): dispatch = critical-CU iter-execs x
// rate (2.0us solo, 1.1us at >=8 waves/CU, 1.0 at 16). R15 failed because
// equal-w pairing DOUBLED critical-CU execs (64x1.1=70us, measured 70-72).
// Here the critical WG = 16 WG-iters of 8-wave width ~= 35us regardless of
// pairing (intra-WG parallelism replaces co-resident-WG parallelism).
// proc/staging/LDS images byte-identical to R15 (passed, absmax 0.0078).

typedef short bf16x8 __attribute__((ext_vector_type(8)));
typedef float f32x4  __attribute__((ext_vector_type(4)));
typedef unsigned short u16;
typedef u16 u16x8 __attribute__((ext_vector_type(8)));

#define MFMA(A,B,C) __builtin_amdgcn_mfma_f32_16x16x32_bf16((A),(B),(C),0,0,0)

__device__ __forceinline__ u16 f2bf_rne(float f) {
    union { float f; unsigned u; } c; c.f = f;
    unsigned r = c.u + 0x7FFFu + ((c.u >> 16) & 1u);
    return (u16)(r >> 16);
}
__device__ __forceinline__ u16 f2bf_fast(float f) {
    union { float f; unsigned u; } c; c.f = f;
    return (u16)((c.u + 0x8000u) >> 16);
}

// ---- fused main: 512 WGs x 512 threads; 128 q-rows; 2 key-groups x 4 waves ----
__global__ __launch_bounds__(512, 4)
void bsattn_fused(const float* __restrict__ Q, const float* __restrict__ K,
                  const float* __restrict__ V, const float* __restrict__ SC,
                  const int* __restrict__ RS, const int* __restrict__ RE,
                  float* __restrict__ O)
{
    constexpr int N = 2048, D = 64;
    int wg = blockIdx.x;
    int bh   = wg & 31;
    int qsub = wg >> 5;                   // [0,16)
    int q0 = qsub << 7;                   // 128-row q tile

    int tid = threadIdx.x;
    int grp = tid >> 8;                   // 0 = low-key group, 1 = high-key group
    int tl  = tid & 255;                  // group-local tid
    int wid = tl >> 6, lane = tl & 63;    // group-local wave, lane
    int n = lane & 15, g = lane >> 4;

    __shared__ __align__(16) u16 lsm[32768];   // 2 groups x 2 x 16KB tile buffers
    __shared__ int sbi[16];

    int row0 = q0 + wid * 32 + n;          // fragment A row (same rows both groups)
    int row1 = row0 + 16;                  // fragment B row
    int rs_l0 = RS[row0], re_l0 = RE[row0];
    int rs_l1 = RS[row1], re_l1 = RE[row1];
    int w_rs_min = min(rs_l0, rs_l1), w_rs_max = max(rs_l0, rs_l1);
    int w_re_min = min(re_l0, re_l1), w_re_max = max(re_l0, re_l1);
    #pragma unroll
    for (int o = 1; o < 16; o <<= 1) {
        w_rs_min = min(w_rs_min, __shfl_xor(w_rs_min, o));
        w_rs_max = max(w_rs_max, __shfl_xor(w_rs_max, o));
        w_re_min = min(w_re_min, __shfl_xor(w_re_min, o));
        w_re_max = max(w_re_max, __shfl_xor(w_re_max, o));
    }
    int wid8 = tid >> 6;                   // WG-wide wave id 0..7
    if (lane == 0) { sbi[wid8 * 2] = w_rs_min; sbi[wid8 * 2 + 1] = w_re_max; }

    float sscale = SC[0] * 1.44269504088896340736f;   // exp2 domain

    bf16x8 qA0, qA1, qB0, qB1;
    {
        const float* qp = Q + ((size_t)bh * N + row0) * D + g * 8;
        float4 a0 = *(const float4*)qp,        a1 = *(const float4*)(qp + 4);
        float4 b0 = *(const float4*)(qp + 32), b1 = *(const float4*)(qp + 36);
        qA0[0]=f2bf_rne(a0.x*sscale); qA0[1]=f2bf_rne(a0.y*sscale);
        qA0[2]=f2bf_rne(a0.z*sscale); qA0[3]=f2bf_rne(a0.w*sscale);
        qA0[4]=f2bf_rne(a1.x*sscale); qA0[5]=f2bf_rne(a1.y*sscale);
        qA0[6]=f2bf_rne(a1.z*sscale); qA0[7]=f2bf_rne(a1.w*sscale);
        qA1[0]=f2bf_rne(b0.x*sscale); qA1[1]=f2bf_rne(b0.y*sscale);
        qA1[2]=f2bf_rne(b0.z*sscale); qA1[3]=f2bf_rne(b0.w*sscale);
        qA1[4]=f2bf_rne(b1.x*sscale); qA1[5]=f2bf_rne(b1.y*sscale);
        qA1[6]=f2bf_rne(b1.z*sscale); qA1[7]=f2bf_rne(b1.w*sscale);
    }
    {
        const float* qp = Q + ((size_t)bh * N + row1) * D + g * 8;
        float4 a0 = *(const float4*)qp,        a1 = *(const float4*)(qp + 4);
        float4 b0 = *(const float4*)(qp + 32), b1 = *(const float4*)(qp + 36);
        qB0[0]=f2bf_rne(a0.x*sscale); qB0[1]=f2bf_rne(a0.y*sscale);
        qB0[2]=f2bf_rne(a0.z*sscale); qB0[3]=f2bf_rne(a0.w*sscale);
        qB0[4]=f2bf_rne(a1.x*sscale); qB0[5]=f2bf_rne(a1.y*sscale);
        qB0[6]=f2bf_rne(a1.z*sscale); qB0[7]=f2bf_rne(a1.w*sscale);
        qB1[0]=f2bf_rne(b0.x*sscale); qB1[1]=f2bf_rne(b0.y*sscale);
        qB1[2]=f2bf_rne(b0.z*sscale); qB1[3]=f2bf_rne(b0.w*sscale);
        qB1[4]=f2bf_rne(b1.x*sscale); qB1[5]=f2bf_rne(b1.y*sscale);
        qB1[6]=f2bf_rne(b1.z*sscale); qB1[7]=f2bf_rne(b1.w*sscale);
    }

    __syncthreads();
    int kst  = min(min(min(sbi[0], sbi[2]),  min(sbi[4],  sbi[6])),
                   min(min(sbi[8], sbi[10]), min(sbi[12], sbi[14]))) & ~63;
    int kend = max(max(max(sbi[1], sbi[3]),  max(sbi[5],  sbi[7])),
                   max(max(sbi[9], sbi[11]), max(sbi[13], sbi[15])));
    int t0 = kst >> 6;
    int w  = (kend - kst + 63) >> 6;       // multiple of 4 here (256-blocks)
    int wl = w >> 1;                       // per-group trip count (>=2), WG-uniform

    // loop-invariant LDS read offsets (u16 indices; verified images)
    int rA   = ((n >> 2) << 3) + (n & 3);
    int phk  = (n & 3) + 4 * ((n >> 2) & 1);
    int osA0 = rA * 64 + ((g + phk) & 7) * 8;
    int osA1 = rA * 64 + ((g + 4 + phk) & 7) * 8;
    int ov0  = 4096 + n * 64 + ((    g + (n & 7)) & 7) * 8;
    int ov1  = 4096 + n * 64 + ((4 + g + (n & 7)) & 7) * 8;

    // loop-invariant STAGING coords (formulas identical to the verified prep kernel,
    // over the 256 threads of THIS group)
    int key_l = tl >> 2, c2 = (tl & 3) << 1;                   // K: thread -> (key, dim-chunk)
    int rotb  = (key_l & 3) + 4 * ((key_l >> 3) & 1);
    int kiA   = key_l * 64 + (((c2    ) + rotb) & 7) * 8;
    int kiB   = key_l * 64 + (((c2 + 1) + rotb) & 7) * 8;
    int kc    = lane >> 3, kw = lane & 7;                      // V: thread -> (key=lane, dims wid*16..)
    const float* Kb = K + (size_t)bh * N * D;
    const float* Vb = V + (size_t)bh * N * D;

    int go = grp << 14;                    // group LDS base (16384 u16 = 2 buffers)

    f32x4 accA[4], accB[4];
    f32x4 acclA = {0.f,0.f,0.f,0.f}, acclB = {0.f,0.f,0.f,0.f};
    #pragma unroll
    for (int c = 0; c < 4; ++c) {
        accA[c] = (f32x4){0.f,0.f,0.f,0.f};
        accB[c] = (f32x4){0.f,0.f,0.f,0.f};
    }
    bf16x8 ones;
    #pragma unroll
    for (int j = 0; j < 8; ++j) ones[j] = (short)0x3F80;

    // in-flight f32 tile staged in registers (issue after barrier, write after proc)
    float4 kf0, kf1, kf2, kf3, vf0, vf1, vf2, vf3;

    auto stage_load = [&](int i) {          // issue f32 loads for group tile i
        if (i < wl) {
            int tile = t0 + grp * wl + i;
            const float* kp = Kb + (size_t)tile * 4096 + key_l * 64 + c2 * 8;
            kf0 = *(const float4*)kp;       kf1 = *(const float4*)(kp + 4);
            kf2 = *(const float4*)(kp + 8); kf3 = *(const float4*)(kp + 12);
            const float* vp = Vb + (size_t)tile * 4096 + lane * 64 + wid * 16;
            vf0 = *(const float4*)vp;       vf1 = *(const float4*)(vp + 4);
            vf2 = *(const float4*)(vp + 8); vf3 = *(const float4*)(vp + 12);
        }
    };
    auto stage_write = [&](int i) {         // cvt + swizzled LDS image write
        if (i < wl) {
            u16* dst = &lsm[go + ((i & 1) << 13)];
            u16x8 a, b;
            a[0]=f2bf_rne(kf0.x); a[1]=f2bf_rne(kf0.y); a[2]=f2bf_rne(kf0.z); a[3]=f2bf_rne(kf0.w);
            a[4]=f2bf_rne(kf1.x); a[5]=f2bf_rne(kf1.y); a[6]=f2bf_rne(kf1.z); a[7]=f2bf_rne(kf1.w);
            b[0]=f2bf_rne(kf2.x); b[1]=f2bf_rne(kf2.y); b[2]=f2bf_rne(kf2.z); b[3]=f2bf_rne(kf2.w);
            b[4]=f2bf_rne(kf3.x); b[5]=f2bf_rne(kf3.y); b[6]=f2bf_rne(kf3.z); b[7]=f2bf_rne(kf3.w);
            *(u16x8*)&dst[kiA] = a;
            *(u16x8*)&dst[kiB] = b;
            float vy[16] = { vf0.x,vf0.y,vf0.z,vf0.w, vf1.x,vf1.y,vf1.z,vf1.w,
                             vf2.x,vf2.y,vf2.z,vf2.w, vf3.x,vf3.y,vf3.z,vf3.w };
            #pragma unroll
            for (int j = 0; j < 16; ++j) {
                int d = wid * 16 + j;
                dst[4096 + d * 64 + ((kc + (j & 7)) & 7) * 8 + kw] = f2bf_rne(vy[j]);
            }
        }
    };

    auto proc = [&](int kb, const u16* ls) {
        bool bdry = (kb < w_rs_max) || (kb + 64 > w_re_min);   // wave-uniform
        #pragma unroll
        for (int h = 0; h < 2; ++h) {
            int hb = h * 2048;
            bf16x8 k00 = *(const bf16x8*)&ls[hb + osA0];
            bf16x8 k01 = *(const bf16x8*)&ls[hb + osA1];
            bf16x8 k10 = *(const bf16x8*)&ls[hb + osA0 + 256];
            bf16x8 k11 = *(const bf16x8*)&ls[hb + osA1 + 256];
            f32x4 tA0 = {0.f,0.f,0.f,0.f}, tA1 = tA0, tB0 = tA0, tB1 = tA0;
            __builtin_amdgcn_s_setprio(1);
            tA0 = MFMA(k00, qA0, tA0); tA0 = MFMA(k01, qA1, tA0);
            tA1 = MFMA(k10, qA0, tA1); tA1 = MFMA(k11, qA1, tA1);
            tB0 = MFMA(k00, qB0, tB0); tB0 = MFMA(k01, qB1, tB0);
            tB1 = MFMA(k10, qB0, tB1); tB1 = MFMA(k11, qB1, tB1);
            __builtin_amdgcn_s_setprio(0);
            float sA[8], sB[8];
            #pragma unroll
            for (int r = 0; r < 4; ++r) {
                sA[r] = tA0[r]; sA[4 + r] = tA1[r];
                sB[r] = tB0[r]; sB[4 + r] = tB1[r];
            }
            if (bdry) {
                #pragma unroll
                for (int j = 0; j < 8; ++j) {
                    int key = kb + h * 32 + g * 8 + j;
                    if (key < rs_l0 || key >= re_l0) sA[j] = -1e30f;
                    if (key < rs_l1 || key >= re_l1) sB[j] = -1e30f;
                }
            }
            bf16x8 pA, pB;
            #pragma unroll
            for (int j = 0; j < 8; ++j) { float p = __builtin_amdgcn_exp2f(sA[j]); pA[j] = (short)f2bf_fast(p); }
            #pragma unroll
            for (int j = 0; j < 8; ++j) { float p = __builtin_amdgcn_exp2f(sB[j]); pB[j] = (short)f2bf_fast(p); }
            int ov = h ? ov1 : ov0;
            bf16x8 v0 = *(const bf16x8*)&ls[ov       ];
            bf16x8 v1 = *(const bf16x8*)&ls[ov + 1024];
            bf16x8 v2 = *(const bf16x8*)&ls[ov + 2048];
            bf16x8 v3 = *(const bf16x8*)&ls[ov + 3072];
            __builtin_amdgcn_s_setprio(1);
            accA[0] = MFMA(pA, v0, accA[0]);
            accA[1] = MFMA(pA, v1, accA[1]);
            accA[2] = MFMA(pA, v2, accA[2]);
            accA[3] = MFMA(pA, v3, accA[3]);
            acclA   = MFMA(pA, ones, acclA);
            accB[0] = MFMA(pB, v0, accB[0]);
            accB[1] = MFMA(pB, v1, accB[1]);
            accB[2] = MFMA(pB, v2, accB[2]);
            accB[3] = MFMA(pB, v3, accB[3]);
            acclB   = MFMA(pB, ones, acclB);
            __builtin_amdgcn_s_setprio(0);
        }
    };

    // prologue: each group's tile 0 staged serially
    stage_load(0);
    stage_write(0);
    for (int i = 0; i < wl; ++i) {          // wl is WG-uniform -> lockstep barriers
        __syncthreads();                    // group buf[i&1] ready; buf[(i+1)&1] free
        stage_load(i + 1);                  // loads covered by proc(i)
        proc(kst + ((grp * wl + i) << 6), &lsm[go + ((i & 1) << 13)]);
        stage_write(i + 1);                 // vmcnt consumed before next barrier
    }

    // ---- merge: group H -> LDS, group L sums + normalizes + writes O ----
    __syncthreads();                        // all procs done; lsm reusable
    float* mf = (float*)lsm;                // 16384 f32 capacity; need <= 10496
    if (grp == 1) {
        int slot = tl * 41;                 // stride 41: conflict-free (gcd(41,32)=1)
        #pragma unroll
        for (int c = 0; c < 4; ++c)
            #pragma unroll
            for (int r = 0; r < 4; ++r) mf[slot + c * 4 + r] = accA[c][r];
        #pragma unroll
        for (int r = 0; r < 4; ++r) mf[slot + 16 + r] = acclA[r];
        #pragma unroll
        for (int c = 0; c < 4; ++c)
            #pragma unroll
            for (int r = 0; r < 4; ++r) mf[slot + 20 + c * 4 + r] = accB[c][r];
        #pragma unroll
        for (int r = 0; r < 4; ++r) mf[slot + 36 + r] = acclB[r];
    }
    __syncthreads();
    if (grp == 0) {
        int slot = tl * 41;
        #pragma unroll
        for (int c = 0; c < 4; ++c)
            #pragma unroll
            for (int r = 0; r < 4; ++r) accA[c][r] += mf[slot + c * 4 + r];
        #pragma unroll
        for (int r = 0; r < 4; ++r) acclA[r] += mf[slot + 16 + r];
        #pragma unroll
        for (int c = 0; c < 4; ++c)
            #pragma unroll
            for (int r = 0; r < 4; ++r) accB[c][r] += mf[slot + 20 + c * 4 + r];
        #pragma unroll
        for (int r = 0; r < 4; ++r) acclB[r] += mf[slot + 36 + r];

        // epilogue: frag A rows q0+wid*32+4g+r, frag B rows +16; cols 16c+n
        int rb = g << 2;
        {
            int orow = q0 + wid * 32 + rb;
            float* ob = O + ((size_t)bh * N + orow) * D + n;
            #pragma unroll
            for (int r = 0; r < 4; ++r) {
                float li = 1.0f / acclA[r];
                float* rp = ob + (size_t)r * D;
                rp[0]  = accA[0][r] * li;
                rp[16] = accA[1][r] * li;
                rp[32] = accA[2][r] * li;
                rp[48] = accA[3][r] * li;
            }
        }
        {
            int orow = q0 + wid * 32 + 16 + rb;
            float* ob = O + ((size_t)bh * N + orow) * D + n;
            #pragma unroll
            for (int r = 0; r < 4; ++r) {
                float li = 1.0f / acclB[r];
                float* rp = ob + (size_t)r * D;
                rp[0]  = accB[0][r] * li;
                rp[16] = accB[1][r] * li;
                rp[32] = accB[2][r] * li;
                rp[48] = accB[3][r] * li;
            }
        }
    }
}

extern "C" void kernel_launch(void* const* d_in, const int* in_sizes, int n_in,
                              void* d_out, int out_size, void* d_ws, size_t ws_size,
                              hipStream_t stream) {
    const float* q  = (const float*)d_in[0];
    const float* k  = (const float*)d_in[1];
    const float* v  = (const float*)d_in[2];
    const float* sc = (const float*)d_in[3];
    const int* rs   = (const int*)d_in[4];
    const int* re   = (const int*)d_in[5];
    float* out      = (float*)d_out;

    bsattn_fused<<<dim3(512), dim3(512), 0, stream>>>(q, k, v, sc, rs, re, out);
}

// Round 17
// 137.751 us; speedup vs baseline: 1.6344x; 1.6344x over previous
//
#include <hip/hip_runtime.h>

// BlockSparseAttention B=2,H=16,N=2048,D=64 fp32, block-causal.
// R22 = R18 resubmitted byte-for-byte (timeouts R13-R16; still unmeasured).
// R18 = R17 with ONE fix: __launch_bounds__(512, 2)  [was (512, 4)].
// R17 post-mortem: (512,4) behaved as 4 blocks/CU = 32 waves/CU -> VGPR budget
// 64 (counter: VGPR_Count=64) -> ~40 live VGPRs spilled -> WRITE 160MB /
// FETCH 113MB scratch traffic -> dispatch 149us. Semantics PINNED by counter:
// 2nd arg ~= blocks/CU here, so (512,2) -> 16 waves/CU -> 128-VGPR budget vs
// ~120 live estimate. (512,1) rejected: no cap -> allocator could drift >128
// -> occupancy collapse to 1 WG/CU (m69: waves halve above 128 VGPR).
// Split-K structure itself VERIFIED (R17 passed, absmax 0.0078125).
// Merge path re-audited r16: stride-41 = (9i+c) mod 32, gcd(9,32)=1 ->
// conflict-free; max idx 10494 f32 < 16384; barrier ordering sound.
// Predicted: VGPR 90-128, WRITE ~16.4MB, FETCH 25-35MB, dispatch 35-48us.
//
// R17 design (unchanged): INTRA-WG SPLIT-K. 512-thread WGs, grid 512.
// Waves 0-3 = key-group L (tiles [0,w/2)), waves 4-7 = group H ([w/2,w)),
// each group owns a 2x16KB double buffer. Both groups trip w/2 exactly ->
// lockstep WG barriers. Epilogue: H -> LDS partials (stride 41), L merges.
// Model: dispatch = critical-CU iter-execs x rate(width); split-K halves the
// critical WG's iters (32->16) at 8-wave width.

typedef short bf16x8 __attribute__((ext_vector_type(8)));
typedef float f32x4  __attribute__((ext_vector_type(4)));
typedef unsigned short u16;
typedef u16 u16x8 __attribute__((ext_vector_type(8)));

#define MFMA(A,B,C) __builtin_amdgcn_mfma_f32_16x16x32_bf16((A),(B),(C),0,0,0)

__device__ __forceinline__ u16 f2bf_rne(float f) {
    union { float f; unsigned u; } c; c.f = f;
    unsigned r = c.u + 0x7FFFu + ((c.u >> 16) & 1u);
    return (u16)(r >> 16);
}
__device__ __forceinline__ u16 f2bf_fast(float f) {
    union { float f; unsigned u; } c; c.f = f;
    return (u16)((c.u + 0x8000u) >> 16);
}

// ---- fused main: 512 WGs x 512 threads; 128 q-rows; 2 key-groups x 4 waves ----
__global__ __launch_bounds__(512, 2)
void bsattn_fused(const float* __restrict__ Q, const float* __restrict__ K,
                  const float* __restrict__ V, const float* __restrict__ SC,
                  const int* __restrict__ RS, const int* __restrict__ RE,
                  float* __restrict__ O)
{
    constexpr int N = 2048, D = 64;
    int wg = blockIdx.x;
    int bh   = wg & 31;
    int qsub = wg >> 5;                   // [0,16)
    int q0 = qsub << 7;                   // 128-row q tile

    int tid = threadIdx.x;
    int grp = tid >> 8;                   // 0 = low-key group, 1 = high-key group
    int tl  = tid & 255;                  // group-local tid
    int wid = tl >> 6, lane = tl & 63;    // group-local wave, lane
    int n = lane & 15, g = lane >> 4;

    __shared__ __align__(16) u16 lsm[32768];   // 2 groups x 2 x 16KB tile buffers
    __shared__ int sbi[16];

    int row0 = q0 + wid * 32 + n;          // fragment A row (same rows both groups)
    int row1 = row0 + 16;                  // fragment B row
    int rs_l0 = RS[row0], re_l0 = RE[row0];
    int rs_l1 = RS[row1], re_l1 = RE[row1];
    int w_rs_min = min(rs_l0, rs_l1), w_rs_max = max(rs_l0, rs_l1);
    int w_re_min = min(re_l0, re_l1), w_re_max = max(re_l0, re_l1);
    #pragma unroll
    for (int o = 1; o < 16; o <<= 1) {
        w_rs_min = min(w_rs_min, __shfl_xor(w_rs_min, o));
        w_rs_max = max(w_rs_max, __shfl_xor(w_rs_max, o));
        w_re_min = min(w_re_min, __shfl_xor(w_re_min, o));
        w_re_max = max(w_re_max, __shfl_xor(w_re_max, o));
    }
    int wid8 = tid >> 6;                   // WG-wide wave id 0..7
    if (lane == 0) { sbi[wid8 * 2] = w_rs_min; sbi[wid8 * 2 + 1] = w_re_max; }

    float sscale = SC[0] * 1.44269504088896340736f;   // exp2 domain

    bf16x8 qA0, qA1, qB0, qB1;
    {
        const float* qp = Q + ((size_t)bh * N + row0) * D + g * 8;
        float4 a0 = *(const float4*)qp,        a1 = *(const float4*)(qp + 4);
        float4 b0 = *(const float4*)(qp + 32), b1 = *(const float4*)(qp + 36);
        qA0[0]=f2bf_rne(a0.x*sscale); qA0[1]=f2bf_rne(a0.y*sscale);
        qA0[2]=f2bf_rne(a0.z*sscale); qA0[3]=f2bf_rne(a0.w*sscale);
        qA0[4]=f2bf_rne(a1.x*sscale); qA0[5]=f2bf_rne(a1.y*sscale);
        qA0[6]=f2bf_rne(a1.z*sscale); qA0[7]=f2bf_rne(a1.w*sscale);
        qA1[0]=f2bf_rne(b0.x*sscale); qA1[1]=f2bf_rne(b0.y*sscale);
        qA1[2]=f2bf_rne(b0.z*sscale); qA1[3]=f2bf_rne(b0.w*sscale);
        qA1[4]=f2bf_rne(b1.x*sscale); qA1[5]=f2bf_rne(b1.y*sscale);
        qA1[6]=f2bf_rne(b1.z*sscale); qA1[7]=f2bf_rne(b1.w*sscale);
    }
    {
        const float* qp = Q + ((size_t)bh * N + row1) * D + g * 8;
        float4 a0 = *(const float4*)qp,        a1 = *(const float4*)(qp + 4);
        float4 b0 = *(const float4*)(qp + 32), b1 = *(const float4*)(qp + 36);
        qB0[0]=f2bf_rne(a0.x*sscale); qB0[1]=f2bf_rne(a0.y*sscale);
        qB0[2]=f2bf_rne(a0.z*sscale); qB0[3]=f2bf_rne(a0.w*sscale);
        qB0[4]=f2bf_rne(a1.x*sscale); qB0[5]=f2bf_rne(a1.y*sscale);
        qB0[6]=f2bf_rne(a1.z*sscale); qB0[7]=f2bf_rne(a1.w*sscale);
        qB1[0]=f2bf_rne(b0.x*sscale); qB1[1]=f2bf_rne(b0.y*sscale);
        qB1[2]=f2bf_rne(b0.z*sscale); qB1[3]=f2bf_rne(b0.w*sscale);
        qB1[4]=f2bf_rne(b1.x*sscale); qB1[5]=f2bf_rne(b1.y*sscale);
        qB1[6]=f2bf_rne(b1.z*sscale); qB1[7]=f2bf_rne(b1.w*sscale);
    }

    __syncthreads();
    int kst  = min(min(min(sbi[0], sbi[2]),  min(sbi[4],  sbi[6])),
                   min(min(sbi[8], sbi[10]), min(sbi[12], sbi[14]))) & ~63;
    int kend = max(max(max(sbi[1], sbi[3]),  max(sbi[5],  sbi[7])),
                   max(max(sbi[9], sbi[11]), max(sbi[13], sbi[15])));
    int t0 = kst >> 6;
    int w  = (kend - kst + 63) >> 6;       // multiple of 4 here (256-blocks)
    int wl = w >> 1;                       // per-group trip count (>=2), WG-uniform

    // loop-invariant LDS read offsets (u16 indices; verified images)
    int rA   = ((n >> 2) << 3) + (n & 3);
    int phk  = (n & 3) + 4 * ((n >> 2) & 1);
    int osA0 = rA * 64 + ((g + phk) & 7) * 8;
    int osA1 = rA * 64 + ((g + 4 + phk) & 7) * 8;
    int ov0  = 4096 + n * 64 + ((    g + (n & 7)) & 7) * 8;
    int ov1  = 4096 + n * 64 + ((4 + g + (n & 7)) & 7) * 8;

    // loop-invariant STAGING coords (formulas identical to the verified prep kernel,
    // over the 256 threads of THIS group)
    int key_l = tl >> 2, c2 = (tl & 3) << 1;                   // K: thread -> (key, dim-chunk)
    int rotb  = (key_l & 3) + 4 * ((key_l >> 3) & 1);
    int kiA   = key_l * 64 + (((c2    ) + rotb) & 7) * 8;
    int kiB   = key_l * 64 + (((c2 + 1) + rotb) & 7) * 8;
    int kc    = lane >> 3, kw = lane & 7;                      // V: thread -> (key=lane, dims wid*16..)
    const float* Kb = K + (size_t)bh * N * D;
    const float* Vb = V + (size_t)bh * N * D;

    int go = grp << 14;                    // group LDS base (16384 u16 = 2 buffers)

    f32x4 accA[4], accB[4];
    f32x4 acclA = {0.f,0.f,0.f,0.f}, acclB = {0.f,0.f,0.f,0.f};
    #pragma unroll
    for (int c = 0; c < 4; ++c) {
        accA[c] = (f32x4){0.f,0.f,0.f,0.f};
        accB[c] = (f32x4){0.f,0.f,0.f,0.f};
    }
    bf16x8 ones;
    #pragma unroll
    for (int j = 0; j < 8; ++j) ones[j] = (short)0x3F80;

    // in-flight f32 tile staged in registers (issue after barrier, write after proc)
    float4 kf0, kf1, kf2, kf3, vf0, vf1, vf2, vf3;

    auto stage_load = [&](int i) {          // issue f32 loads for group tile i
        if (i < wl) {
            int tile = t0 + grp * wl + i;
            const float* kp = Kb + (size_t)tile * 4096 + key_l * 64 + c2 * 8;
            kf0 = *(const float4*)kp;       kf1 = *(const float4*)(kp + 4);
            kf2 = *(const float4*)(kp + 8); kf3 = *(const float4*)(kp + 12);
            const float* vp = Vb + (size_t)tile * 4096 + lane * 64 + wid * 16;
            vf0 = *(const float4*)vp;       vf1 = *(const float4*)(vp + 4);
            vf2 = *(const float4*)(vp + 8); vf3 = *(const float4*)(vp + 12);
        }
    };
    auto stage_write = [&](int i) {         // cvt + swizzled LDS image write
        if (i < wl) {
            u16* dst = &lsm[go + ((i & 1) << 13)];
            u16x8 a, b;
            a[0]=f2bf_rne(kf0.x); a[1]=f2bf_rne(kf0.y); a[2]=f2bf_rne(kf0.z); a[3]=f2bf_rne(kf0.w);
            a[4]=f2bf_rne(kf1.x); a[5]=f2bf_rne(kf1.y); a[6]=f2bf_rne(kf1.z); a[7]=f2bf_rne(kf1.w);
            b[0]=f2bf_rne(kf2.x); b[1]=f2bf_rne(kf2.y); b[2]=f2bf_rne(kf2.z); b[3]=f2bf_rne(kf2.w);
            b[4]=f2bf_rne(kf3.x); b[5]=f2bf_rne(kf3.y); b[6]=f2bf_rne(kf3.z); b[7]=f2bf_rne(kf3.w);
            *(u16x8*)&dst[kiA] = a;
            *(u16x8*)&dst[kiB] = b;
            float vy[16] = { vf0.x,vf0.y,vf0.z,vf0.w, vf1.x,vf1.y,vf1.z,vf1.w,
                             vf2.x,vf2.y,vf2.z,vf2.w, vf3.x,vf3.y,vf3.z,vf3.w };
            #pragma unroll
            for (int j = 0; j < 16; ++j) {
                int d = wid * 16 + j;
                dst[4096 + d * 64 + ((kc + (j & 7)) & 7) * 8 + kw] = f2bf_rne(vy[j]);
            }
        }
    };

    auto proc = [&](int kb, const u16* ls) {
        bool bdry = (kb < w_rs_max) || (kb + 64 > w_re_min);   // wave-uniform
        #pragma unroll
        for (int h = 0; h < 2; ++h) {
            int hb = h * 2048;
            bf16x8 k00 = *(const bf16x8*)&ls[hb + osA0];
            bf16x8 k01 = *(const bf16x8*)&ls[hb + osA1];
            bf16x8 k10 = *(const bf16x8*)&ls[hb + osA0 + 256];
            bf16x8 k11 = *(const bf16x8*)&ls[hb + osA1 + 256];
            f32x4 tA0 = {0.f,0.f,0.f,0.f}, tA1 = tA0, tB0 = tA0, tB1 = tA0;
            __builtin_amdgcn_s_setprio(1);
            tA0 = MFMA(k00, qA0, tA0); tA0 = MFMA(k01, qA1, tA0);
            tA1 = MFMA(k10, qA0, tA1); tA1 = MFMA(k11, qA1, tA1);
            tB0 = MFMA(k00, qB0, tB0); tB0 = MFMA(k01, qB1, tB0);
            tB1 = MFMA(k10, qB0, tB1); tB1 = MFMA(k11, qB1, tB1);
            __builtin_amdgcn_s_setprio(0);
            float sA[8], sB[8];
            #pragma unroll
            for (int r = 0; r < 4; ++r) {
                sA[r] = tA0[r]; sA[4 + r] = tA1[r];
                sB[r] = tB0[r]; sB[4 + r] = tB1[r];
            }
            if (bdry) {
                #pragma unroll
                for (int j = 0; j < 8; ++j) {
                    int key = kb + h * 32 + g * 8 + j;
                    if (key < rs_l0 || key >= re_l0) sA[j] = -1e30f;
                    if (key < rs_l1 || key >= re_l1) sB[j] = -1e30f;
                }
            }
            bf16x8 pA, pB;
            #pragma unroll
            for (int j = 0; j < 8; ++j) { float p = __builtin_amdgcn_exp2f(sA[j]); pA[j] = (short)f2bf_fast(p); }
            #pragma unroll
            for (int j = 0; j < 8; ++j) { float p = __builtin_amdgcn_exp2f(sB[j]); pB[j] = (short)f2bf_fast(p); }
            int ov = h ? ov1 : ov0;
            bf16x8 v0 = *(const bf16x8*)&ls[ov       ];
            bf16x8 v1 = *(const bf16x8*)&ls[ov + 1024];
            bf16x8 v2 = *(const bf16x8*)&ls[ov + 2048];
            bf16x8 v3 = *(const bf16x8*)&ls[ov + 3072];
            __builtin_amdgcn_s_setprio(1);
            accA[0] = MFMA(pA, v0, accA[0]);
            accA[1] = MFMA(pA, v1, accA[1]);
            accA[2] = MFMA(pA, v2, accA[2]);
            accA[3] = MFMA(pA, v3, accA[3]);
            acclA   = MFMA(pA, ones, acclA);
            accB[0] = MFMA(pB, v0, accB[0]);
            accB[1] = MFMA(pB, v1, accB[1]);
            accB[2] = MFMA(pB, v2, accB[2]);
            accB[3] = MFMA(pB, v3, accB[3]);
            acclB   = MFMA(pB, ones, acclB);
            __builtin_amdgcn_s_setprio(0);
        }
    };

    // prologue: each group's tile 0 staged serially
    stage_load(0);
    stage_write(0);
    for (int i = 0; i < wl; ++i) {          // wl is WG-uniform -> lockstep barriers
        __syncthreads();                    // group buf[i&1] ready; buf[(i+1)&1] free
        stage_load(i + 1);                  // loads covered by proc(i)
        proc(kst + ((grp * wl + i) << 6), &lsm[go + ((i & 1) << 13)]);
        stage_write(i + 1);                 // vmcnt consumed before next barrier
    }

    // ---- merge: group H -> LDS, group L sums + normalizes + writes O ----
    __syncthreads();                        // all procs done; lsm reusable
    float* mf = (float*)lsm;                // 16384 f32 capacity; need <= 10495
    if (grp == 1) {
        int slot = tl * 41;                 // bank = (9*lane+c)%32, gcd(9,32)=1 -> conflict-free
        #pragma unroll
        for (int c = 0; c < 4; ++c)
            #pragma unroll
            for (int r = 0; r < 4; ++r) mf[slot + c * 4 + r] = accA[c][r];
        #pragma unroll
        for (int r = 0; r < 4; ++r) mf[slot + 16 + r] = acclA[r];
        #pragma unroll
        for (int c = 0; c < 4; ++c)
            #pragma unroll
            for (int r = 0; r < 4; ++r) mf[slot + 20 + c * 4 + r] = accB[c][r];
        #pragma unroll
        for (int r = 0; r < 4; ++r) mf[slot + 36 + r] = acclB[r];
    }
    __syncthreads();
    if (grp == 0) {
        int slot = tl * 41;
        #pragma unroll
        for (int c = 0; c < 4; ++c)
            #pragma unroll
            for (int r = 0; r < 4; ++r) accA[c][r] += mf[slot + c * 4 + r];
        #pragma unroll
        for (int r = 0; r < 4; ++r) acclA[r] += mf[slot + 16 + r];
        #pragma unroll
        for (int c = 0; c < 4; ++c)
            #pragma unroll
            for (int r = 0; r < 4; ++r) accB[c][r] += mf[slot + 20 + c * 4 + r];
        #pragma unroll
        for (int r = 0; r < 4; ++r) acclB[r] += mf[slot + 36 + r];

        // epilogue: frag A rows q0+wid*32+4g+r, frag B rows +16; cols 16c+n
        int rb = g << 2;
        {
            int orow = q0 + wid * 32 + rb;
            float* ob = O + ((size_t)bh * N + orow) * D + n;
            #pragma unroll
            for (int r = 0; r < 4; ++r) {
                float li = 1.0f / acclA[r];
                float* rp = ob + (size_t)r * D;
                rp[0]  = accA[0][r] * li;
                rp[16] = accA[1][r] * li;
                rp[32] = accA[2][r] * li;
                rp[48] = accA[3][r] * li;
            }
        }
        {
            int orow = q0 + wid * 32 + 16 + rb;
            float* ob = O + ((size_t)bh * N + orow) * D + n;
            #pragma unroll
            for (int r = 0; r < 4; ++r) {
                float li = 1.0f / acclB[r];
                float* rp = ob + (size_t)r * D;
                rp[0]  = accB[0][r] * li;
                rp[16] = accB[1][r] * li;
                rp[32] = accB[2][r] * li;
                rp[48] = accB[3][r] * li;
            }
        }
    }
}

extern "C" void kernel_launch(void* const* d_in, const int* in_sizes, int n_in,
                              void* d_out, int out_size, void* d_ws, size_t ws_size,
                              hipStream_t stream) {
    const float* q  = (const float*)d_in[0];
    const float* k  = (const float*)d_in[1];
    const float* v  = (const float*)d_in[2];
    const float* sc = (const float*)d_in[3];
    const int* rs   = (const int*)d_in[4];
    const int* re   = (const int*)d_in[5];
    float* out      = (float*)d_out;

    bsattn_fused<<<dim3(512), dim3(512), 0, stream>>>(q, k, v, sc, rs, re, out);
}

// Round 18
// 127.749 us; speedup vs baseline: 1.7623x; 1.0783x over previous
//
#include <hip/hip_runtime.h>

// BlockSparseAttention B=2,H=16,N=2048,D=64 fp32, block-causal.
// R23 = R18 (measured: 65us dispatch, VGPR 80, spill GONE - WRITE 16.4MB exact)
//     + ONE change: balanced {q,15-q} CU pairing map (3 lines).
// Model (fits R12/R13/R15/R17/R18 within 5%): dispatch = critical-CU total
// tile-procs x rate; rate ~1.0-1.35us at >=8 waves, 2.0 solo-4-wave.
// R18's map paired qsub {q, q+8} -> critical CU {15,7} = 48 procs -> 65us.
// w(qsub) = 4*(floor(q/2)+1); total 9216 procs / 256 CUs = 36 ideal.
// {q,15-q}: w(q)+w(15-q) = 36 for EVERY CU (floor halves sum to 7).
// Map: lo=wg&255, hi=wg>>8; qsub = hi ? 15-(lo>>4) : lo>>4; bh=(lo&15)+(hi<<4).
// Coverage: each (bh,qsub) exactly once; wg & wg+256 share a CU (round-robin,
// evidenced by R15/R18 fits). Critical CU = {15,0} pair: heavy WG ~15 rounds
// nearly solo at 8-wave/2-stream (~2.0-2.2us/round) -> ~33-38us.
// Predicted: dispatch 33-45us, total 100-115us, VGPR 80, WRITE 16.4MB.
// Failure reads: 55-65 -> pairing assumption wrong -> dynamic queue next;
// 45-55 -> solo-8-wave rate worse -> attack per-round latency; absmax -> map bug.
//
// Design (unchanged, verified): INTRA-WG SPLIT-K. 512-thread WGs, grid 512.
// Waves 0-3 = key-group L (tiles [0,w/2)), waves 4-7 = H ([w/2,w)), each group
// owns a 2x16KB double buffer (66KB LDS -> 2 WGs/CU). Lockstep WG barriers.
// Epilogue: H -> LDS partials (stride 41, conflict-free), L merges + writes O.

typedef short bf16x8 __attribute__((ext_vector_type(8)));
typedef float f32x4  __attribute__((ext_vector_type(4)));
typedef unsigned short u16;
typedef u16 u16x8 __attribute__((ext_vector_type(8)));

#define MFMA(A,B,C) __builtin_amdgcn_mfma_f32_16x16x32_bf16((A),(B),(C),0,0,0)

__device__ __forceinline__ u16 f2bf_rne(float f) {
    union { float f; unsigned u; } c; c.f = f;
    unsigned r = c.u + 0x7FFFu + ((c.u >> 16) & 1u);
    return (u16)(r >> 16);
}
__device__ __forceinline__ u16 f2bf_fast(float f) {
    union { float f; unsigned u; } c; c.f = f;
    return (u16)((c.u + 0x8000u) >> 16);
}

// ---- fused main: 512 WGs x 512 threads; 128 q-rows; 2 key-groups x 4 waves ----
__global__ __launch_bounds__(512, 2)
void bsattn_fused(const float* __restrict__ Q, const float* __restrict__ K,
                  const float* __restrict__ V, const float* __restrict__ SC,
                  const int* __restrict__ RS, const int* __restrict__ RE,
                  float* __restrict__ O)
{
    constexpr int N = 2048, D = 64;
    int wg = blockIdx.x;
    // balanced pairing: CU c hosts wg=c and wg=c+256 with qsub q and 15-q
    // -> per-CU tile-procs = w(q)+w(15-q) = 36 uniformly.
    int lo = wg & 255, hi = wg >> 8;
    int qs = lo >> 4;                     // [0,16)
    int qsub = hi ? (15 - qs) : qs;
    int bh   = (lo & 15) + (hi << 4);
    int q0 = qsub << 7;                   // 128-row q tile

    int tid = threadIdx.x;
    int grp = tid >> 8;                   // 0 = low-key group, 1 = high-key group
    int tl  = tid & 255;                  // group-local tid
    int wid = tl >> 6, lane = tl & 63;    // group-local wave, lane
    int n = lane & 15, g = lane >> 4;

    __shared__ __align__(16) u16 lsm[32768];   // 2 groups x 2 x 16KB tile buffers
    __shared__ int sbi[16];

    int row0 = q0 + wid * 32 + n;          // fragment A row (same rows both groups)
    int row1 = row0 + 16;                  // fragment B row
    int rs_l0 = RS[row0], re_l0 = RE[row0];
    int rs_l1 = RS[row1], re_l1 = RE[row1];
    int w_rs_min = min(rs_l0, rs_l1), w_rs_max = max(rs_l0, rs_l1);
    int w_re_min = min(re_l0, re_l1), w_re_max = max(re_l0, re_l1);
    #pragma unroll
    for (int o = 1; o < 16; o <<= 1) {
        w_rs_min = min(w_rs_min, __shfl_xor(w_rs_min, o));
        w_rs_max = max(w_rs_max, __shfl_xor(w_rs_max, o));
        w_re_min = min(w_re_min, __shfl_xor(w_re_min, o));
        w_re_max = max(w_re_max, __shfl_xor(w_re_max, o));
    }
    int wid8 = tid >> 6;                   // WG-wide wave id 0..7
    if (lane == 0) { sbi[wid8 * 2] = w_rs_min; sbi[wid8 * 2 + 1] = w_re_max; }

    float sscale = SC[0] * 1.44269504088896340736f;   // exp2 domain

    bf16x8 qA0, qA1, qB0, qB1;
    {
        const float* qp = Q + ((size_t)bh * N + row0) * D + g * 8;
        float4 a0 = *(const float4*)qp,        a1 = *(const float4*)(qp + 4);
        float4 b0 = *(const float4*)(qp + 32), b1 = *(const float4*)(qp + 36);
        qA0[0]=f2bf_rne(a0.x*sscale); qA0[1]=f2bf_rne(a0.y*sscale);
        qA0[2]=f2bf_rne(a0.z*sscale); qA0[3]=f2bf_rne(a0.w*sscale);
        qA0[4]=f2bf_rne(a1.x*sscale); qA0[5]=f2bf_rne(a1.y*sscale);
        qA0[6]=f2bf_rne(a1.z*sscale); qA0[7]=f2bf_rne(a1.w*sscale);
        qA1[0]=f2bf_rne(b0.x*sscale); qA1[1]=f2bf_rne(b0.y*sscale);
        qA1[2]=f2bf_rne(b0.z*sscale); qA1[3]=f2bf_rne(b0.w*sscale);
        qA1[4]=f2bf_rne(b1.x*sscale); qA1[5]=f2bf_rne(b1.y*sscale);
        qA1[6]=f2bf_rne(b1.z*sscale); qA1[7]=f2bf_rne(b1.w*sscale);
    }
    {
        const float* qp = Q + ((size_t)bh * N + row1) * D + g * 8;
        float4 a0 = *(const float4*)qp,        a1 = *(const float4*)(qp + 4);
        float4 b0 = *(const float4*)(qp + 32), b1 = *(const float4*)(qp + 36);
        qB0[0]=f2bf_rne(a0.x*sscale); qB0[1]=f2bf_rne(a0.y*sscale);
        qB0[2]=f2bf_rne(a0.z*sscale); qB0[3]=f2bf_rne(a0.w*sscale);
        qB0[4]=f2bf_rne(a1.x*sscale); qB0[5]=f2bf_rne(a1.y*sscale);
        qB0[6]=f2bf_rne(a1.z*sscale); qB0[7]=f2bf_rne(a1.w*sscale);
        qB1[0]=f2bf_rne(b0.x*sscale); qB1[1]=f2bf_rne(b0.y*sscale);
        qB1[2]=f2bf_rne(b0.z*sscale); qB1[3]=f2bf_rne(b0.w*sscale);
        qB1[4]=f2bf_rne(b1.x*sscale); qB1[5]=f2bf_rne(b1.y*sscale);
        qB1[6]=f2bf_rne(b1.z*sscale); qB1[7]=f2bf_rne(b1.w*sscale);
    }

    __syncthreads();
    int kst  = min(min(min(sbi[0], sbi[2]),  min(sbi[4],  sbi[6])),
                   min(min(sbi[8], sbi[10]), min(sbi[12], sbi[14]))) & ~63;
    int kend = max(max(max(sbi[1], sbi[3]),  max(sbi[5],  sbi[7])),
                   max(max(sbi[9], sbi[11]), max(sbi[13], sbi[15])));
    int t0 = kst >> 6;
    int w  = (kend - kst + 63) >> 6;       // multiple of 4 (256-blocks)
    int wl = w >> 1;                       // per-group trip count (>=2), WG-uniform

    // loop-invariant LDS read offsets (u16 indices; verified images)
    int rA   = ((n >> 2) << 3) + (n & 3);
    int phk  = (n & 3) + 4 * ((n >> 2) & 1);
    int osA0 = rA * 64 + ((g + phk) & 7) * 8;
    int osA1 = rA * 64 + ((g + 4 + phk) & 7) * 8;
    int ov0  = 4096 + n * 64 + ((    g + (n & 7)) & 7) * 8;
    int ov1  = 4096 + n * 64 + ((4 + g + (n & 7)) & 7) * 8;

    // loop-invariant STAGING coords (formulas identical to the verified prep kernel,
    // over the 256 threads of THIS group)
    int key_l = tl >> 2, c2 = (tl & 3) << 1;                   // K: thread -> (key, dim-chunk)
    int rotb  = (key_l & 3) + 4 * ((key_l >> 3) & 1);
    int kiA   = key_l * 64 + (((c2    ) + rotb) & 7) * 8;
    int kiB   = key_l * 64 + (((c2 + 1) + rotb) & 7) * 8;
    int kc    = lane >> 3, kw = lane & 7;                      // V: thread -> (key=lane, dims wid*16..)
    const float* Kb = K + (size_t)bh * N * D;
    const float* Vb = V + (size_t)bh * N * D;

    int go = grp << 14;                    // group LDS base (16384 u16 = 2 buffers)

    f32x4 accA[4], accB[4];
    f32x4 acclA = {0.f,0.f,0.f,0.f}, acclB = {0.f,0.f,0.f,0.f};
    #pragma unroll
    for (int c = 0; c < 4; ++c) {
        accA[c] = (f32x4){0.f,0.f,0.f,0.f};
        accB[c] = (f32x4){0.f,0.f,0.f,0.f};
    }
    bf16x8 ones;
    #pragma unroll
    for (int j = 0; j < 8; ++j) ones[j] = (short)0x3F80;

    // in-flight f32 tile staged in registers (issue after barrier, write after proc)
    float4 kf0, kf1, kf2, kf3, vf0, vf1, vf2, vf3;

    auto stage_load = [&](int i) {          // issue f32 loads for group tile i
        if (i < wl) {
            int tile = t0 + grp * wl + i;
            const float* kp = Kb + (size_t)tile * 4096 + key_l * 64 + c2 * 8;
            kf0 = *(const float4*)kp;       kf1 = *(const float4*)(kp + 4);
            kf2 = *(const float4*)(kp + 8); kf3 = *(const float4*)(kp + 12);
            const float* vp = Vb + (size_t)tile * 4096 + lane * 64 + wid * 16;
            vf0 = *(const float4*)vp;       vf1 = *(const float4*)(vp + 4);
            vf2 = *(const float4*)(vp + 8); vf3 = *(const float4*)(vp + 12);
        }
    };
    auto stage_write = [&](int i) {         // cvt + swizzled LDS image write
        if (i < wl) {
            u16* dst = &lsm[go + ((i & 1) << 13)];
            u16x8 a, b;
            a[0]=f2bf_rne(kf0.x); a[1]=f2bf_rne(kf0.y); a[2]=f2bf_rne(kf0.z); a[3]=f2bf_rne(kf0.w);
            a[4]=f2bf_rne(kf1.x); a[5]=f2bf_rne(kf1.y); a[6]=f2bf_rne(kf1.z); a[7]=f2bf_rne(kf1.w);
            b[0]=f2bf_rne(kf2.x); b[1]=f2bf_rne(kf2.y); b[2]=f2bf_rne(kf2.z); b[3]=f2bf_rne(kf2.w);
            b[4]=f2bf_rne(kf3.x); b[5]=f2bf_rne(kf3.y); b[6]=f2bf_rne(kf3.z); b[7]=f2bf_rne(kf3.w);
            *(u16x8*)&dst[kiA] = a;
            *(u16x8*)&dst[kiB] = b;
            float vy[16] = { vf0.x,vf0.y,vf0.z,vf0.w, vf1.x,vf1.y,vf1.z,vf1.w,
                             vf2.x,vf2.y,vf2.z,vf2.w, vf3.x,vf3.y,vf3.z,vf3.w };
            #pragma unroll
            for (int j = 0; j < 16; ++j) {
                int d = wid * 16 + j;
                dst[4096 + d * 64 + ((kc + (j & 7)) & 7) * 8 + kw] = f2bf_rne(vy[j]);
            }
        }
    };

    auto proc = [&](int kb, const u16* ls) {
        bool bdry = (kb < w_rs_max) || (kb + 64 > w_re_min);   // wave-uniform
        #pragma unroll
        for (int h = 0; h < 2; ++h) {
            int hb = h * 2048;
            bf16x8 k00 = *(const bf16x8*)&ls[hb + osA0];
            bf16x8 k01 = *(const bf16x8*)&ls[hb + osA1];
            bf16x8 k10 = *(const bf16x8*)&ls[hb + osA0 + 256];
            bf16x8 k11 = *(const bf16x8*)&ls[hb + osA1 + 256];
            f32x4 tA0 = {0.f,0.f,0.f,0.f}, tA1 = tA0, tB0 = tA0, tB1 = tA0;
            __builtin_amdgcn_s_setprio(1);
            tA0 = MFMA(k00, qA0, tA0); tA0 = MFMA(k01, qA1, tA0);
            tA1 = MFMA(k10, qA0, tA1); tA1 = MFMA(k11, qA1, tA1);
            tB0 = MFMA(k00, qB0, tB0); tB0 = MFMA(k01, qB1, tB0);
            tB1 = MFMA(k10, qB0, tB1); tB1 = MFMA(k11, qB1, tB1);
            __builtin_amdgcn_s_setprio(0);
            float sA[8], sB[8];
            #pragma unroll
            for (int r = 0; r < 4; ++r) {
                sA[r] = tA0[r]; sA[4 + r] = tA1[r];
                sB[r] = tB0[r]; sB[4 + r] = tB1[r];
            }
            if (bdry) {
                #pragma unroll
                for (int j = 0; j < 8; ++j) {
                    int key = kb + h * 32 + g * 8 + j;
                    if (key < rs_l0 || key >= re_l0) sA[j] = -1e30f;
                    if (key < rs_l1 || key >= re_l1) sB[j] = -1e30f;
                }
            }
            bf16x8 pA, pB;
            #pragma unroll
            for (int j = 0; j < 8; ++j) { float p = __builtin_amdgcn_exp2f(sA[j]); pA[j] = (short)f2bf_fast(p); }
            #pragma unroll
            for (int j = 0; j < 8; ++j) { float p = __builtin_amdgcn_exp2f(sB[j]); pB[j] = (short)f2bf_fast(p); }
            int ov = h ? ov1 : ov0;
            bf16x8 v0 = *(const bf16x8*)&ls[ov       ];
            bf16x8 v1 = *(const bf16x8*)&ls[ov + 1024];
            bf16x8 v2 = *(const bf16x8*)&ls[ov + 2048];
            bf16x8 v3 = *(const bf16x8*)&ls[ov + 3072];
            __builtin_amdgcn_s_setprio(1);
            accA[0] = MFMA(pA, v0, accA[0]);
            accA[1] = MFMA(pA, v1, accA[1]);
            accA[2] = MFMA(pA, v2, accA[2]);
            accA[3] = MFMA(pA, v3, accA[3]);
            acclA   = MFMA(pA, ones, acclA);
            accB[0] = MFMA(pB, v0, accB[0]);
            accB[1] = MFMA(pB, v1, accB[1]);
            accB[2] = MFMA(pB, v2, accB[2]);
            accB[3] = MFMA(pB, v3, accB[3]);
            acclB   = MFMA(pB, ones, acclB);
            __builtin_amdgcn_s_setprio(0);
        }
    };

    // prologue: each group's tile 0 staged serially
    stage_load(0);
    stage_write(0);
    for (int i = 0; i < wl; ++i) {          // wl is WG-uniform -> lockstep barriers
        __syncthreads();                    // group buf[i&1] ready; buf[(i+1)&1] free
        stage_load(i + 1);                  // loads covered by proc(i)
        proc(kst + ((grp * wl + i) << 6), &lsm[go + ((i & 1) << 13)]);
        stage_write(i + 1);                 // vmcnt consumed before next barrier
    }

    // ---- merge: group H -> LDS, group L sums + normalizes + writes O ----
    __syncthreads();                        // all procs done; lsm reusable
    float* mf = (float*)lsm;                // 16384 f32 capacity; need <= 10495
    if (grp == 1) {
        int slot = tl * 41;                 // bank = (9*lane+c)%32, gcd(9,32)=1 -> conflict-free
        #pragma unroll
        for (int c = 0; c < 4; ++c)
            #pragma unroll
            for (int r = 0; r < 4; ++r) mf[slot + c * 4 + r] = accA[c][r];
        #pragma unroll
        for (int r = 0; r < 4; ++r) mf[slot + 16 + r] = acclA[r];
        #pragma unroll
        for (int c = 0; c < 4; ++c)
            #pragma unroll
            for (int r = 0; r < 4; ++r) mf[slot + 20 + c * 4 + r] = accB[c][r];
        #pragma unroll
        for (int r = 0; r < 4; ++r) mf[slot + 36 + r] = acclB[r];
    }
    __syncthreads();
    if (grp == 0) {
        int slot = tl * 41;
        #pragma unroll
        for (int c = 0; c < 4; ++c)
            #pragma unroll
            for (int r = 0; r < 4; ++r) accA[c][r] += mf[slot + c * 4 + r];
        #pragma unroll
        for (int r = 0; r < 4; ++r) acclA[r] += mf[slot + 16 + r];
        #pragma unroll
        for (int c = 0; c < 4; ++c)
            #pragma unroll
            for (int r = 0; r < 4; ++r) accB[c][r] += mf[slot + 20 + c * 4 + r];
        #pragma unroll
        for (int r = 0; r < 4; ++r) acclB[r] += mf[slot + 36 + r];

        // epilogue: frag A rows q0+wid*32+4g+r, frag B rows +16; cols 16c+n
        int rb = g << 2;
        {
            int orow = q0 + wid * 32 + rb;
            float* ob = O + ((size_t)bh * N + orow) * D + n;
            #pragma unroll
            for (int r = 0; r < 4; ++r) {
                float li = 1.0f / acclA[r];
                float* rp = ob + (size_t)r * D;
                rp[0]  = accA[0][r] * li;
                rp[16] = accA[1][r] * li;
                rp[32] = accA[2][r] * li;
                rp[48] = accA[3][r] * li;
            }
        }
        {
            int orow = q0 + wid * 32 + 16 + rb;
            float* ob = O + ((size_t)bh * N + orow) * D + n;
            #pragma unroll
            for (int r = 0; r < 4; ++r) {
                float li = 1.0f / acclB[r];
                float* rp = ob + (size_t)r * D;
                rp[0]  = accB[0][r] * li;
                rp[16] = accB[1][r] * li;
                rp[32] = accB[2][r] * li;
                rp[48] = accB[3][r] * li;
            }
        }
    }
}

extern "C" void kernel_launch(void* const* d_in, const int* in_sizes, int n_in,
                              void* d_out, int out_size, void* d_ws, size_t ws_size,
                              hipStream_t stream) {
    const float* q  = (const float*)d_in[0];
    const float* k  = (const float*)d_in[1];
    const float* v  = (const float*)d_in[2];
    const float* sc = (const float*)d_in[3];
    const int* rs   = (const int*)d_in[4];
    const int* re   = (const int*)d_in[5];
    float* out      = (float*)d_out;

    bsattn_fused<<<dim3(512), dim3(512), 0, stream>>>(q, k, v, sc, rs, re, out);
}